// Round 3
// baseline (1220.236 us; speedup 1.0000x reference)
//
#include <hip/hip_runtime.h>
#include <cstdint>
#include <cstddef>

#define N_NODES 50000
#define M_PAD   50176   // 392 * 128
#define EPS_BN  1e-5f
#define NEG     0.2f

typedef __attribute__((ext_vector_type(8))) short bf16x8;
typedef __attribute__((ext_vector_type(4))) float f32x4;

// ---------- bf16 helpers ----------
static __device__ __forceinline__ ushort f2bf(float f) {
    unsigned u = __float_as_uint(f);
    unsigned r = (u + 0x7FFFu + ((u >> 16) & 1u)) >> 16;   // RNE
    return (ushort)r;
}
static __device__ __forceinline__ float bf2f(ushort b) {
    return __uint_as_float(((unsigned)b) << 16);
}
// order-preserving float<->uint for atomicMax
static __device__ __forceinline__ unsigned encf(float f) {
    unsigned u = __float_as_uint(f);
    return (u & 0x80000000u) ? ~u : (u | 0x80000000u);
}
static __device__ __forceinline__ float decf(unsigned v) {
    return (v & 0x80000000u) ? __uint_as_float(v ^ 0x80000000u)
                             : __uint_as_float(~v);
}

// ---------- input conversion: x fp32 [N,256] -> bf16 padded [M_PAD,256] ----------
__global__ void conv_x(const float* __restrict__ x, ushort* __restrict__ out) {
    const int i = blockIdx.x * 256 + threadIdx.x;
    const int e0 = i * 4;
    if (e0 >= M_PAD * 256) return;
    const int row = e0 >> 8;
    ushort4 o;
    if (row < N_NODES) {
        const float4 v = *(const float4*)&x[e0];
        o = make_ushort4(f2bf(v.x), f2bf(v.y), f2bf(v.z), f2bf(v.w));
    } else {
        o = make_ushort4(0, 0, 0, 0);
    }
    *(ushort4*)&out[e0] = o;
}

// ---------- weight convert + transpose: W fp32 [K,Nc] -> Wt bf16 [Nc,K] ----------
__global__ void convT(const float* __restrict__ W, ushort* __restrict__ Wt,
                      int K, int Nc) {
    const int i = blockIdx.x * 256 + threadIdx.x;
    if (i < K * Nc) {
        const int k = i / Nc, n = i - k * Nc;
        Wt[(size_t)n * K + k] = f2bf(W[i]);
    }
}

// ---------- MFMA GEMM: C[M_PAD,Nc] = A[M_PAD,K] * Bt[Nc,K]^T, all bf16, fp32 acc ----------
__global__ __launch_bounds__(256) void gemm_bf16(
    const ushort* __restrict__ A, const ushort* __restrict__ Bt,
    ushort* __restrict__ C, int K, int Nc) {
    __shared__ ushort As[128 * 32];
    __shared__ ushort Bs[64 * 32];
    const int t = threadIdx.x;
    const int wave = t >> 6, lane = t & 63;
    const int quad = lane >> 4, l16 = lane & 15;
    const int m0 = blockIdx.y * 128, n0 = blockIdx.x * 64;

    const int aRow = t >> 2, aCol = (t & 3) * 8;
    const ushort* aG0 = A + (size_t)(m0 + aRow) * K + aCol;
    const ushort* aG1 = A + (size_t)(m0 + 64 + aRow) * K + aCol;
    const ushort* bG  = Bt + (size_t)(n0 + aRow) * K + aCol;

    const int aOff0 = (wave * 32 + l16) * 32 + quad * 8;
    const int aOff1 = aOff0 + 16 * 32;
    const int bOff  = l16 * 32 + quad * 8;

    f32x4 acc[2][4] = {};
    for (int k0 = 0; k0 < K; k0 += 32) {
        const uint4 a0 = *(const uint4*)(aG0 + k0);
        const uint4 a1 = *(const uint4*)(aG1 + k0);
        const uint4 b0 = *(const uint4*)(bG + k0);
        __syncthreads();
        *(uint4*)&As[t * 8]        = a0;
        *(uint4*)&As[2048 + t * 8] = a1;
        *(uint4*)&Bs[t * 8]        = b0;
        __syncthreads();
        const bf16x8 af0 = *(const bf16x8*)&As[aOff0];
        const bf16x8 af1 = *(const bf16x8*)&As[aOff1];
#pragma unroll
        for (int nt = 0; nt < 4; ++nt) {
            const bf16x8 bf = *(const bf16x8*)&Bs[bOff + nt * 512];
            acc[0][nt] = __builtin_amdgcn_mfma_f32_16x16x32_bf16(af0, bf, acc[0][nt], 0, 0, 0);
            acc[1][nt] = __builtin_amdgcn_mfma_f32_16x16x32_bf16(af1, bf, acc[1][nt], 0, 0, 0);
        }
    }
    const int rowBase = m0 + wave * 32;
#pragma unroll
    for (int mt = 0; mt < 2; ++mt) {
#pragma unroll
        for (int nt = 0; nt < 4; ++nt) {
            const int col = n0 + nt * 16 + l16;
#pragma unroll
            for (int r = 0; r < 4; ++r) {
                const int row = rowBase + mt * 16 + quad * 4 + r;
                C[(size_t)row * Nc + col] = f2bf(acc[mt][nt][r]);
            }
        }
    }
}

// ---------- per-node attention scores s,d : [N,H], h is bf16 ----------
template <int H>
__global__ __launch_bounds__(128) void scores_kernel(
    const ushort* __restrict__ h, const float* __restrict__ a_src,
    const float* __restrict__ a_dst, float* __restrict__ s,
    float* __restrict__ d) {
    const int n = blockIdx.x, t = threadIdx.x;
    if (t < 32 * H) {
        const int head = t >> 5;
        const int c0 = (t & 31) * 4;
        const ushort4 hv = *(const ushort4*)&h[(size_t)n * (H * 128) + head * 128 + c0];
        const float4 as = *(const float4*)&a_src[head * 128 + c0];
        const float4 ad = *(const float4*)&a_dst[head * 128 + c0];
        const float h0 = bf2f(hv.x), h1 = bf2f(hv.y), h2 = bf2f(hv.z), h3 = bf2f(hv.w);
        float ps = h0 * as.x + h1 * as.y + h2 * as.z + h3 * as.w;
        float pd = h0 * ad.x + h1 * ad.y + h2 * ad.z + h3 * ad.w;
#pragma unroll
        for (int m = 16; m >= 1; m >>= 1) {
            ps += __shfl_xor(ps, m, 32);
            pd += __shfl_xor(pd, m, 32);
        }
        if ((t & 31) == 0) {
            s[n * H + head] = ps;
            d[n * H + head] = pd;
        }
    }
}

// ---------- CSR build ----------
__global__ void edge_hist(const int* __restrict__ ei, int E, int* __restrict__ cnt) {
    const int k = blockIdx.x * blockDim.x + threadIdx.x;
    const int ET = E + N_NODES;
    if (k < ET) {
        const int dstn = (k < E) ? ei[E + k] : (k - E);
        atomicAdd(&cnt[dstn], 1);
    }
}

__global__ __launch_bounds__(256) void scan_phase1(
    const int* __restrict__ cnt, int* __restrict__ incl,
    int* __restrict__ bsum, int n) {
    __shared__ int sh[256];
    const int b = blockIdx.x, t = threadIdx.x;
    const int i0 = b * 1024 + t * 4;
    int v[4]; int sum = 0;
#pragma unroll
    for (int k = 0; k < 4; ++k) {
        v[k] = (i0 + k < n) ? cnt[i0 + k] : 0;
        sum += v[k];
    }
    sh[t] = sum;
    __syncthreads();
    for (int off = 1; off < 256; off <<= 1) {
        const int a = (t >= off) ? sh[t - off] : 0;
        __syncthreads();
        sh[t] += a;
        __syncthreads();
    }
    int run = sh[t] - sum;
#pragma unroll
    for (int k = 0; k < 4; ++k) {
        run += v[k];
        if (i0 + k < n) incl[i0 + k] = run;
    }
    if (t == 255) bsum[b] = sh[255];
}

__global__ void scan_phase2(int* __restrict__ bsum, int nb) {
    if (threadIdx.x == 0) {
        int run = 0;
        for (int i = 0; i < nb; ++i) { const int v = bsum[i]; bsum[i] = run; run += v; }
    }
}

__global__ void scan_phase3(const int* __restrict__ incl, const int* __restrict__ boffs,
                            int* __restrict__ rowptr, int* __restrict__ cursor, int n) {
    const int i = blockIdx.x * 256 + threadIdx.x;
    if (i < n) {
        rowptr[i + 1] = incl[i] + boffs[i >> 10];
        cursor[i] = (i == 0) ? 0 : (incl[i - 1] + boffs[(i - 1) >> 10]);
    }
    if (i == 0) rowptr[0] = 0;
}

__global__ void edge_scatter(const int* __restrict__ ei, int E,
                             int* __restrict__ cursor, int* __restrict__ col,
                             int* __restrict__ dstA) {
    const int k = blockIdx.x * blockDim.x + threadIdx.x;
    const int ET = E + N_NODES;
    if (k < ET) {
        const int srcn = (k < E) ? ei[k] : (k - E);
        const int dstn = (k < E) ? ei[E + k] : (k - E);
        const int p = atomicAdd(&cursor[dstn], 1);
        col[p] = srcn;
        dstA[p] = dstn;
    }
}

// ---------- edge-parallel softmax: pass A (leaky score + segment max) ----------
template <int H>
__global__ void edge_scoreA(const int* __restrict__ col, const int* __restrict__ dstA,
                            int ET, const float* __restrict__ s,
                            const float* __restrict__ d, float* __restrict__ eArr,
                            unsigned* __restrict__ emax) {
    const int p = blockIdx.x * 256 + threadIdx.x;
    if (p >= ET) return;
    const int sn = col[p], dn = dstA[p];
    if constexpr (H == 4) {
        const float4 sv = *(const float4*)&s[sn * 4];
        const float4 dv = *(const float4*)&d[dn * 4];
        float4 ev;
        ev.x = sv.x + dv.x; ev.x = (ev.x > 0.f) ? ev.x : NEG * ev.x;
        ev.y = sv.y + dv.y; ev.y = (ev.y > 0.f) ? ev.y : NEG * ev.y;
        ev.z = sv.z + dv.z; ev.z = (ev.z > 0.f) ? ev.z : NEG * ev.z;
        ev.w = sv.w + dv.w; ev.w = (ev.w > 0.f) ? ev.w : NEG * ev.w;
        *(float4*)&eArr[p * 4] = ev;
        atomicMax(&emax[dn * 4 + 0], encf(ev.x));
        atomicMax(&emax[dn * 4 + 1], encf(ev.y));
        atomicMax(&emax[dn * 4 + 2], encf(ev.z));
        atomicMax(&emax[dn * 4 + 3], encf(ev.w));
    } else {
        float e = s[sn] + d[dn];
        e = (e > 0.f) ? e : NEG * e;
        eArr[p] = e;
        atomicMax(&emax[dn], encf(e));
    }
}

// ---------- edge-parallel softmax: pass B (exp + segment sum) ----------
template <int H>
__global__ void edge_scoreB(const int* __restrict__ dstA, int ET,
                            const unsigned* __restrict__ emax,
                            float* __restrict__ eArr, float* __restrict__ den) {
    const int p = blockIdx.x * 256 + threadIdx.x;
    if (p >= ET) return;
    const int dn = dstA[p];
    if constexpr (H == 4) {
        float4 ev = *(const float4*)&eArr[p * 4];
        ev.x = __expf(ev.x - decf(emax[dn * 4 + 0]));
        ev.y = __expf(ev.y - decf(emax[dn * 4 + 1]));
        ev.z = __expf(ev.z - decf(emax[dn * 4 + 2]));
        ev.w = __expf(ev.w - decf(emax[dn * 4 + 3]));
        *(float4*)&eArr[p * 4] = ev;
        atomicAdd(&den[dn * 4 + 0], ev.x);
        atomicAdd(&den[dn * 4 + 1], ev.y);
        atomicAdd(&den[dn * 4 + 2], ev.z);
        atomicAdd(&den[dn * 4 + 3], ev.w);
    } else {
        const float ex = __expf(eArr[p] - decf(emax[dn]));
        eArr[p] = ex;
        atomicAdd(&den[dn], ex);
    }
}

// ---------- aggregation H=4: one block (2 waves) per node, single pass ----------
__global__ __launch_bounds__(128) void aggregate4(
    const ushort* __restrict__ h, const float* __restrict__ exA,
    const float* __restrict__ den, const int* __restrict__ rowptr,
    const int* __restrict__ col, const float* __restrict__ bias,
    float* __restrict__ y) {
    const int n = blockIdx.x, t = threadIdx.x;
    const int w = t >> 6, lane = t & 63;
    const int head = lane >> 4;
    const int rs = rowptr[n], re = rowptr[n + 1];
    float acc[8];
#pragma unroll
    for (int k = 0; k < 8; ++k) acc[k] = 0.f;

    int j = rs + w;
    int srcn = (j < re) ? col[j] : 0;
    while (j < re) {
        const int jn = j + 2;
        const int srcn_n = (jn < re) ? col[jn] : 0;
        const float e = exA[j * 4 + head];
        const bf16x8 hv = *(const bf16x8*)&h[(size_t)srcn * 512 + lane * 8];
#pragma unroll
        for (int k = 0; k < 8; ++k) acc[k] = fmaf(e, bf2f((ushort)hv[k]), acc[k]);
        srcn = srcn_n;
        j = jn;
    }
    __shared__ float sh[512];
    if (w == 0) {
#pragma unroll
        for (int k = 0; k < 8; ++k) sh[lane * 8 + k] = acc[k];
    }
    __syncthreads();
    if (w == 1) {
#pragma unroll
        for (int k = 0; k < 8; ++k) sh[lane * 8 + k] += acc[k];
    }
    __syncthreads();
    if (t < 32) {
        const float4 dn4 = *(const float4*)&den[n * 4];
        const float i0 = 1.f / (dn4.x + 1e-16f);
        const float i1 = 1.f / (dn4.y + 1e-16f);
        const float i2 = 1.f / (dn4.z + 1e-16f);
        const float i3 = 1.f / (dn4.w + 1e-16f);
        const int c0 = t * 4;
#pragma unroll
        for (int v = 0; v < 4; ++v) {
            const int c = c0 + v;
            const float m = 0.25f * (sh[c] * i0 + sh[128 + c] * i1 +
                                     sh[256 + c] * i2 + sh[384 + c] * i3);
            y[(size_t)n * 128 + c] = m + bias[c];
        }
    }
}

// ---------- aggregation H=1 ----------
__global__ __launch_bounds__(128) void aggregate1(
    const ushort* __restrict__ h, const float* __restrict__ exA,
    const float* __restrict__ den, const int* __restrict__ rowptr,
    const int* __restrict__ col, const float* __restrict__ bias,
    float* __restrict__ y) {
    const int n = blockIdx.x, t = threadIdx.x;
    const int w = t >> 6, lane = t & 63;
    const int rs = rowptr[n], re = rowptr[n + 1];
    float acc0 = 0.f, acc1 = 0.f;
    int j = rs + w;
    int srcn = (j < re) ? col[j] : 0;
    while (j < re) {
        const int jn = j + 2;
        const int srcn_n = (jn < re) ? col[jn] : 0;
        const float e = exA[j];
        const ushort2 hv = *(const ushort2*)&h[(size_t)srcn * 128 + lane * 2];
        acc0 = fmaf(e, bf2f(hv.x), acc0);
        acc1 = fmaf(e, bf2f(hv.y), acc1);
        srcn = srcn_n;
        j = jn;
    }
    __shared__ float sh[128];
    if (w == 0) { sh[lane * 2] = acc0; sh[lane * 2 + 1] = acc1; }
    __syncthreads();
    if (w == 1) { sh[lane * 2] += acc0; sh[lane * 2 + 1] += acc1; }
    __syncthreads();
    const float inv = 1.f / (den[n] + 1e-16f);
    y[(size_t)n * 128 + t] = sh[t] * inv + bias[t];
}

// ---------- BatchNorm ----------
__global__ __launch_bounds__(256) void bn_stats1(
    const float* __restrict__ y, float* __restrict__ partial, int nblocks) {
    const int b = blockIdx.x, t = threadIdx.x;
    const int c = t & 127;
    float sum = 0.f, sq = 0.f;
    for (int r = b * 2 + (t >> 7); r < N_NODES; r += nblocks * 2) {
        const float v = y[(size_t)r * 128 + c];
        sum += v;
        sq += v * v;
    }
    __shared__ float s1[256], s2[256];
    s1[t] = sum; s2[t] = sq;
    __syncthreads();
    if (t < 128) {
        partial[(size_t)b * 256 + c] = s1[t] + s1[t + 128];
        partial[(size_t)b * 256 + 128 + c] = s2[t] + s2[t + 128];
    }
}

__global__ __launch_bounds__(128) void bn_stats2(
    const float* __restrict__ partial, int nblocks,
    const float* __restrict__ gamma, const float* __restrict__ beta,
    float* __restrict__ stats) {
    const int c = threadIdx.x;
    float S = 0.f, Q = 0.f;
    for (int b = 0; b < nblocks; ++b) {
        S += partial[(size_t)b * 256 + c];
        Q += partial[(size_t)b * 256 + 128 + c];
    }
    const float mu = S / (float)N_NODES;
    const float var = Q / (float)N_NODES - mu * mu;
    const float sc = gamma[c] * rsqrtf(var + EPS_BN);
    stats[c] = sc;
    stats[128 + c] = beta[c] - mu * sc;
}

__global__ void bn_apply_bf16(const float* __restrict__ y,
                              const float* __restrict__ stats,
                              ushort* __restrict__ out) {
    const int i = blockIdx.x * 256 + threadIdx.x;
    const int e0 = i * 4;
    if (e0 >= M_PAD * 128) return;
    const int row = e0 >> 7;
    ushort4 o;
    if (row < N_NODES) {
        const float4 v = *(const float4*)&y[e0];
        const int c = e0 & 127;
        const float a = fmaxf(v.x * stats[c]     + stats[128 + c],     0.f);
        const float b = fmaxf(v.y * stats[c + 1] + stats[128 + c + 1], 0.f);
        const float cc = fmaxf(v.z * stats[c + 2] + stats[128 + c + 2], 0.f);
        const float d = fmaxf(v.w * stats[c + 3] + stats[128 + c + 3], 0.f);
        o = make_ushort4(f2bf(a), f2bf(b), f2bf(cc), f2bf(d));
    } else {
        o = make_ushort4(0, 0, 0, 0);
    }
    *(ushort4*)&out[e0] = o;
}

__global__ void bn_apply_out(const float* __restrict__ y,
                             const float* __restrict__ stats,
                             float* __restrict__ out) {
    const int i = blockIdx.x * blockDim.x + threadIdx.x;
    if (i < N_NODES * 128) {
        const int c = i & 127;
        out[i] = y[i] * stats[c] + stats[128 + c];
    }
}

// ---------- launch ----------
extern "C" void kernel_launch(void* const* d_in, const int* in_sizes, int n_in,
                              void* d_out, int out_size, void* d_ws, size_t ws_size,
                              hipStream_t stream) {
    const float* x = (const float*)d_in[0];
    const int* ei = (const int*)d_in[1];
    const int E = in_sizes[1] / 2;
    const int ET = E + N_NODES;

    const float* W[3]    = {(const float*)d_in[2], (const float*)d_in[8],  (const float*)d_in[14]};
    const float* ASRC[3] = {(const float*)d_in[3], (const float*)d_in[9],  (const float*)d_in[15]};
    const float* ADST[3] = {(const float*)d_in[4], (const float*)d_in[10], (const float*)d_in[16]};
    const float* BIAS[3] = {(const float*)d_in[5], (const float*)d_in[11], (const float*)d_in[17]};
    const float* GAM[3]  = {(const float*)d_in[6], (const float*)d_in[12], (const float*)d_in[18]};
    const float* BET[3]  = {(const float*)d_in[7], (const float*)d_in[13], (const float*)d_in[19]};

    char* base = (char*)d_ws;
    auto alloc = [&](size_t bytes) {
        char* p = base;
        base += (bytes + 255) & ~(size_t)255;
        return p;
    };
    ushort* hbf    = (ushort*)alloc((size_t)M_PAD * 512 * 2);
    ushort* Xbf    = (ushort*)alloc((size_t)M_PAD * 256 * 2);   // exA aliases this
    ushort* Wt     = (ushort*)alloc((size_t)512 * 256 * 2);
    float*  y      = (float*)alloc((size_t)N_NODES * 128 * 4);
    float*  s      = (float*)alloc((size_t)N_NODES * 4 * 4);
    float*  dsc    = (float*)alloc((size_t)N_NODES * 4 * 4);
    unsigned* emax = (unsigned*)alloc((size_t)N_NODES * 4 * 4);
    float*  den    = (float*)alloc((size_t)N_NODES * 4 * 4);
    int*    rowptr = (int*)alloc((size_t)(N_NODES + 1) * 4);
    int*    col    = (int*)alloc((size_t)ET * 4);
    int*    dstA   = (int*)alloc((size_t)ET * 4);
    int*    cnt    = (int*)alloc((size_t)N_NODES * 4);          // reused as cursor
    int*    incl   = (int*)alloc((size_t)N_NODES * 4);
    int*    bsum   = (int*)alloc((size_t)64 * 4);
    float*  partial = (float*)alloc((size_t)256 * 256 * 4);
    float*  stats   = (float*)alloc((size_t)256 * 4);
    if ((size_t)(base - (char*)d_ws) > ws_size) return;

    // exA aliases Xbf: valid because for each layer exA is written strictly after
    // that layer's gemm consumed Xbf, and bn_apply_bf16 rewrites Xbf only after
    // aggregate has consumed exA (stream-ordered).
    float* exA = (float*)Xbf;   // needs ET*4*4 = 7.2 MB <= 25.7 MB

    const int eb = (ET + 255) / 256;
    const int nScanB = (N_NODES + 1023) / 1024;

    // --- CSR build ---
    hipMemsetAsync(cnt, 0, (size_t)N_NODES * 4, stream);
    edge_hist<<<eb, 256, 0, stream>>>(ei, E, cnt);
    scan_phase1<<<nScanB, 256, 0, stream>>>(cnt, incl, bsum, N_NODES);
    scan_phase2<<<1, 64, 0, stream>>>(bsum, nScanB);
    scan_phase3<<<(N_NODES + 255) / 256, 256, 0, stream>>>(incl, bsum, rowptr, cnt, N_NODES);
    edge_scatter<<<eb, 256, 0, stream>>>(ei, E, cnt, col, dstA);

    // --- layer-0 input to bf16 (padded) ---
    conv_x<<<(M_PAD * 256 / 4 + 255) / 256, 256, 0, stream>>>(x, Xbf);

    const int Hs[3]  = {4, 4, 1};
    const int Kin[3] = {256, 128, 128};

    for (int L = 0; L < 3; ++L) {
        const int H = Hs[L], K = Kin[L], Nc = H * 128;

        convT<<<(K * Nc + 255) / 256, 256, 0, stream>>>(W[L], Wt, K, Nc);
        dim3 ggrid(Nc / 64, M_PAD / 128);
        gemm_bf16<<<ggrid, 256, 0, stream>>>(Xbf, Wt, hbf, K, Nc);

        hipMemsetAsync(emax, 0, (size_t)N_NODES * 4 * 4, stream);
        hipMemsetAsync(den,  0, (size_t)N_NODES * 4 * 4, stream);

        if (H == 4) {
            scores_kernel<4><<<N_NODES, 128, 0, stream>>>(hbf, ASRC[L], ADST[L], s, dsc);
            edge_scoreA<4><<<eb, 256, 0, stream>>>(col, dstA, ET, s, dsc, exA, emax);
            edge_scoreB<4><<<eb, 256, 0, stream>>>(dstA, ET, emax, exA, den);
            aggregate4<<<N_NODES, 128, 0, stream>>>(hbf, exA, den, rowptr, col, BIAS[L], y);
        } else {
            scores_kernel<1><<<N_NODES, 128, 0, stream>>>(hbf, ASRC[L], ADST[L], s, dsc);
            edge_scoreA<1><<<eb, 256, 0, stream>>>(col, dstA, ET, s, dsc, exA, emax);
            edge_scoreB<1><<<eb, 256, 0, stream>>>(dstA, ET, emax, exA, den);
            aggregate1<<<N_NODES, 128, 0, stream>>>(hbf, exA, den, rowptr, col, BIAS[L], y);
        }

        bn_stats1<<<256, 256, 0, stream>>>(y, partial, 256);
        bn_stats2<<<1, 128, 0, stream>>>(partial, 256, GAM[L], BET[L], stats);

        if (L < 2) {
            bn_apply_bf16<<<(M_PAD * 128 / 4 + 255) / 256, 256, 0, stream>>>(y, stats, Xbf);
        } else {
            bn_apply_out<<<(N_NODES * 128 + 255) / 256, 256, 0, stream>>>(y, stats, (float*)d_out);
        }
    }
}

// Round 4
// 774.521 us; speedup vs baseline: 1.5755x; 1.5755x over previous
//
#include <hip/hip_runtime.h>
#include <cstdint>
#include <cstddef>

#define N_NODES 50000
#define M_PAD   50176   // 392 * 128
#define EPS_BN  1e-5f
#define NEG     0.2f

typedef __attribute__((ext_vector_type(8))) short bf16x8;
typedef __attribute__((ext_vector_type(4))) float f32x4;

// ---------- bf16 helpers ----------
static __device__ __forceinline__ ushort f2bf(float f) {
    unsigned u = __float_as_uint(f);
    unsigned r = (u + 0x7FFFu + ((u >> 16) & 1u)) >> 16;   // RNE
    return (ushort)r;
}
static __device__ __forceinline__ float bf2f(ushort b) {
    return __uint_as_float(((unsigned)b) << 16);
}

// ---------- input conversion: x fp32 [N,256] -> bf16 padded [M_PAD,256] ----------
__global__ void conv_x(const float* __restrict__ x, ushort* __restrict__ out) {
    const int i = blockIdx.x * 256 + threadIdx.x;
    const int e0 = i * 4;
    if (e0 >= M_PAD * 256) return;
    const int row = e0 >> 8;
    ushort4 o;
    if (row < N_NODES) {
        const float4 v = *(const float4*)&x[e0];
        o = make_ushort4(f2bf(v.x), f2bf(v.y), f2bf(v.z), f2bf(v.w));
    } else {
        o = make_ushort4(0, 0, 0, 0);
    }
    *(ushort4*)&out[e0] = o;
}

// ---------- weight convert + transpose: W fp32 [K,Nc] -> Wt bf16 [Nc,K] ----------
__global__ void convT(const float* __restrict__ W, ushort* __restrict__ Wt,
                      int K, int Nc) {
    const int i = blockIdx.x * 256 + threadIdx.x;
    if (i < K * Nc) {
        const int k = i / Nc, n = i - k * Nc;
        Wt[(size_t)n * K + k] = f2bf(W[i]);
    }
}

// ---------- MFMA GEMM: C[M_PAD,Nc] = A[M_PAD,K] * Bt[Nc,K]^T, all bf16, fp32 acc ----------
__global__ __launch_bounds__(256) void gemm_bf16(
    const ushort* __restrict__ A, const ushort* __restrict__ Bt,
    ushort* __restrict__ C, int K, int Nc) {
    __shared__ ushort As[128 * 32];
    __shared__ ushort Bs[64 * 32];
    const int t = threadIdx.x;
    const int wave = t >> 6, lane = t & 63;
    const int quad = lane >> 4, l16 = lane & 15;
    const int m0 = blockIdx.y * 128, n0 = blockIdx.x * 64;

    const int aRow = t >> 2, aCol = (t & 3) * 8;
    const ushort* aG0 = A + (size_t)(m0 + aRow) * K + aCol;
    const ushort* aG1 = A + (size_t)(m0 + 64 + aRow) * K + aCol;
    const ushort* bG  = Bt + (size_t)(n0 + aRow) * K + aCol;

    const int aOff0 = (wave * 32 + l16) * 32 + quad * 8;
    const int aOff1 = aOff0 + 16 * 32;
    const int bOff  = l16 * 32 + quad * 8;

    f32x4 acc[2][4] = {};
    for (int k0 = 0; k0 < K; k0 += 32) {
        const uint4 a0 = *(const uint4*)(aG0 + k0);
        const uint4 a1 = *(const uint4*)(aG1 + k0);
        const uint4 b0 = *(const uint4*)(bG + k0);
        __syncthreads();
        *(uint4*)&As[t * 8]        = a0;
        *(uint4*)&As[2048 + t * 8] = a1;
        *(uint4*)&Bs[t * 8]        = b0;
        __syncthreads();
        const bf16x8 af0 = *(const bf16x8*)&As[aOff0];
        const bf16x8 af1 = *(const bf16x8*)&As[aOff1];
#pragma unroll
        for (int nt = 0; nt < 4; ++nt) {
            const bf16x8 bf = *(const bf16x8*)&Bs[bOff + nt * 512];
            acc[0][nt] = __builtin_amdgcn_mfma_f32_16x16x32_bf16(af0, bf, acc[0][nt], 0, 0, 0);
            acc[1][nt] = __builtin_amdgcn_mfma_f32_16x16x32_bf16(af1, bf, acc[1][nt], 0, 0, 0);
        }
    }
    const int rowBase = m0 + wave * 32;
#pragma unroll
    for (int mt = 0; mt < 2; ++mt) {
#pragma unroll
        for (int nt = 0; nt < 4; ++nt) {
            const int col = n0 + nt * 16 + l16;
#pragma unroll
            for (int r = 0; r < 4; ++r) {
                const int row = rowBase + mt * 16 + quad * 4 + r;
                C[(size_t)row * Nc + col] = f2bf(acc[mt][nt][r]);
            }
        }
    }
}

// ---------- per-node attention scores s,d : [N,H], h is bf16 ----------
template <int H>
__global__ __launch_bounds__(128) void scores_kernel(
    const ushort* __restrict__ h, const float* __restrict__ a_src,
    const float* __restrict__ a_dst, float* __restrict__ s,
    float* __restrict__ d) {
    const int n = blockIdx.x, t = threadIdx.x;
    if (t < 32 * H) {
        const int head = t >> 5;
        const int c0 = (t & 31) * 4;
        const ushort4 hv = *(const ushort4*)&h[(size_t)n * (H * 128) + head * 128 + c0];
        const float4 as = *(const float4*)&a_src[head * 128 + c0];
        const float4 ad = *(const float4*)&a_dst[head * 128 + c0];
        const float h0 = bf2f(hv.x), h1 = bf2f(hv.y), h2 = bf2f(hv.z), h3 = bf2f(hv.w);
        float ps = h0 * as.x + h1 * as.y + h2 * as.z + h3 * as.w;
        float pd = h0 * ad.x + h1 * ad.y + h2 * ad.z + h3 * ad.w;
#pragma unroll
        for (int m = 16; m >= 1; m >>= 1) {
            ps += __shfl_xor(ps, m, 32);
            pd += __shfl_xor(pd, m, 32);
        }
        if ((t & 31) == 0) {
            s[n * H + head] = ps;
            d[n * H + head] = pd;
        }
    }
}

// ---------- CSR build ----------
__global__ void edge_hist(const int* __restrict__ ei, int E, int* __restrict__ cnt) {
    const int k = blockIdx.x * blockDim.x + threadIdx.x;
    const int ET = E + N_NODES;
    if (k < ET) {
        const int dstn = (k < E) ? ei[E + k] : (k - E);
        atomicAdd(&cnt[dstn], 1);
    }
}

__global__ __launch_bounds__(256) void scan_phase1(
    const int* __restrict__ cnt, int* __restrict__ incl,
    int* __restrict__ bsum, int n) {
    __shared__ int sh[256];
    const int b = blockIdx.x, t = threadIdx.x;
    const int i0 = b * 1024 + t * 4;
    int v[4]; int sum = 0;
#pragma unroll
    for (int k = 0; k < 4; ++k) {
        v[k] = (i0 + k < n) ? cnt[i0 + k] : 0;
        sum += v[k];
    }
    sh[t] = sum;
    __syncthreads();
    for (int off = 1; off < 256; off <<= 1) {
        const int a = (t >= off) ? sh[t - off] : 0;
        __syncthreads();
        sh[t] += a;
        __syncthreads();
    }
    int run = sh[t] - sum;
#pragma unroll
    for (int k = 0; k < 4; ++k) {
        run += v[k];
        if (i0 + k < n) incl[i0 + k] = run;
    }
    if (t == 255) bsum[b] = sh[255];
}

__global__ void scan_phase2(int* __restrict__ bsum, int nb) {
    if (threadIdx.x == 0) {
        int run = 0;
        for (int i = 0; i < nb; ++i) { const int v = bsum[i]; bsum[i] = run; run += v; }
    }
}

__global__ void scan_phase3(const int* __restrict__ incl, const int* __restrict__ boffs,
                            int* __restrict__ rowptr, int* __restrict__ cursor, int n) {
    const int i = blockIdx.x * 256 + threadIdx.x;
    if (i < n) {
        rowptr[i + 1] = incl[i] + boffs[i >> 10];
        cursor[i] = (i == 0) ? 0 : (incl[i - 1] + boffs[(i - 1) >> 10]);
    }
    if (i == 0) rowptr[0] = 0;
}

// col order within a row is irrelevant: max/sum are order-independent.
__global__ void edge_scatter(const int* __restrict__ ei, int E,
                             int* __restrict__ cursor, int* __restrict__ col) {
    const int k = blockIdx.x * blockDim.x + threadIdx.x;
    const int ET = E + N_NODES;
    if (k < ET) {
        const int srcn = (k < E) ? ei[k] : (k - E);
        const int dstn = (k < E) ? ei[E + k] : (k - E);
        const int p = atomicAdd(&cursor[dstn], 1);
        col[p] = srcn;
    }
}

// ---------- aggregation H=4: ONE WAVE per dst node, cooperative softmax ----------
// lanes stride the edge list for max/exp (computed once per edge), ex parked in
// LDS; gather loop reads ex via LDS broadcast and FMAs 16B/lane h slices.
__global__ __launch_bounds__(64) void aggregate4(
    const ushort* __restrict__ h, const float* __restrict__ s,
    const float* __restrict__ d, const int* __restrict__ rowptr,
    const int* __restrict__ col, const float* __restrict__ bias,
    float* __restrict__ y) {
    const int n = blockIdx.x, lane = threadIdx.x;
    const int rs = rowptr[n], re = rowptr[n + 1];
    const float4 dn = *(const float4*)&d[n * 4];
    __shared__ int   ls[256];
    __shared__ float lex[256 * 4];
    __shared__ float lout[512];

    // pass A: per-head max (cooperative + wave allreduce)
    float4 mx = make_float4(-3.4e38f, -3.4e38f, -3.4e38f, -3.4e38f);
    for (int j = rs + lane; j < re; j += 64) {
        const float4 sv = *(const float4*)&s[col[j] * 4];
        float ex_ = sv.x + dn.x; ex_ = (ex_ > 0.f) ? ex_ : NEG * ex_;
        float ey_ = sv.y + dn.y; ey_ = (ey_ > 0.f) ? ey_ : NEG * ey_;
        float ez_ = sv.z + dn.z; ez_ = (ez_ > 0.f) ? ez_ : NEG * ez_;
        float ew_ = sv.w + dn.w; ew_ = (ew_ > 0.f) ? ew_ : NEG * ew_;
        mx.x = fmaxf(mx.x, ex_); mx.y = fmaxf(mx.y, ey_);
        mx.z = fmaxf(mx.z, ez_); mx.w = fmaxf(mx.w, ew_);
    }
#pragma unroll
    for (int off = 1; off < 64; off <<= 1) {
        mx.x = fmaxf(mx.x, __shfl_xor(mx.x, off));
        mx.y = fmaxf(mx.y, __shfl_xor(mx.y, off));
        mx.z = fmaxf(mx.z, __shfl_xor(mx.z, off));
        mx.w = fmaxf(mx.w, __shfl_xor(mx.w, off));
    }

    // pass B (chunked): exp once per edge -> LDS; gather-FMA
    const int head = lane >> 4;
    float4 dsum = make_float4(0.f, 0.f, 0.f, 0.f);
    float acc[8];
#pragma unroll
    for (int k = 0; k < 8; ++k) acc[k] = 0.f;

    for (int c0 = rs; c0 < re; c0 += 256) {
        const int cend = min(re, c0 + 256);
        for (int j = c0 + lane; j < cend; j += 64) {
            const int sn = col[j];
            const float4 sv = *(const float4*)&s[sn * 4];
            float ex_ = sv.x + dn.x; ex_ = (ex_ > 0.f) ? ex_ : NEG * ex_;
            float ey_ = sv.y + dn.y; ey_ = (ey_ > 0.f) ? ey_ : NEG * ey_;
            float ez_ = sv.z + dn.z; ez_ = (ez_ > 0.f) ? ez_ : NEG * ez_;
            float ew_ = sv.w + dn.w; ew_ = (ew_ > 0.f) ? ew_ : NEG * ew_;
            float4 ex4;
            ex4.x = __expf(ex_ - mx.x); ex4.y = __expf(ey_ - mx.y);
            ex4.z = __expf(ez_ - mx.z); ex4.w = __expf(ew_ - mx.w);
            const int jj = j - c0;
            ls[jj] = sn;
            *(float4*)&lex[jj * 4] = ex4;
            dsum.x += ex4.x; dsum.y += ex4.y; dsum.z += ex4.z; dsum.w += ex4.w;
        }
        __syncthreads();
        const int cnum = cend - c0;
        for (int jj = 0; jj < cnum; ++jj) {
            const int sn = ls[jj];
            const float exh = lex[jj * 4 + head];
            const bf16x8 hv = *(const bf16x8*)&h[(size_t)sn * 512 + lane * 8];
#pragma unroll
            for (int k = 0; k < 8; ++k) acc[k] = fmaf(exh, bf2f((ushort)hv[k]), acc[k]);
        }
        __syncthreads();
    }

    // denominator allreduce
#pragma unroll
    for (int off = 1; off < 64; off <<= 1) {
        dsum.x += __shfl_xor(dsum.x, off);
        dsum.y += __shfl_xor(dsum.y, off);
        dsum.z += __shfl_xor(dsum.z, off);
        dsum.w += __shfl_xor(dsum.w, off);
    }
    const float dh[4] = {dsum.x, dsum.y, dsum.z, dsum.w};
    const float inv = 1.f / (dh[head] + 1e-16f);
#pragma unroll
    for (int k = 0; k < 8; ++k) lout[lane * 8 + k] = acc[k] * inv;
    __syncthreads();
    // head mean + bias: lane -> cols lane*2, lane*2+1
    {
        const int c = lane * 2;
        const float m0 = 0.25f * (lout[c] + lout[128 + c] + lout[256 + c] + lout[384 + c]);
        const float m1 = 0.25f * (lout[c + 1] + lout[128 + c + 1] + lout[256 + c + 1] + lout[384 + c + 1]);
        float2 o = make_float2(m0 + bias[c], m1 + bias[c + 1]);
        *(float2*)&y[(size_t)n * 128 + c] = o;
    }
}

// ---------- aggregation H=1: one wave per node ----------
__global__ __launch_bounds__(64) void aggregate1(
    const ushort* __restrict__ h, const float* __restrict__ s,
    const float* __restrict__ d, const int* __restrict__ rowptr,
    const int* __restrict__ col, const float* __restrict__ bias,
    float* __restrict__ y) {
    const int n = blockIdx.x, lane = threadIdx.x;
    const int rs = rowptr[n], re = rowptr[n + 1];
    const float dn = d[n];
    __shared__ int   ls[256];
    __shared__ float lex[256];

    float mx = -3.4e38f;
    for (int j = rs + lane; j < re; j += 64) {
        float e = s[col[j]] + dn;
        e = (e > 0.f) ? e : NEG * e;
        mx = fmaxf(mx, e);
    }
#pragma unroll
    for (int off = 1; off < 64; off <<= 1) mx = fmaxf(mx, __shfl_xor(mx, off));

    float dsum = 0.f;
    float acc0 = 0.f, acc1 = 0.f;
    for (int c0 = rs; c0 < re; c0 += 256) {
        const int cend = min(re, c0 + 256);
        for (int j = c0 + lane; j < cend; j += 64) {
            const int sn = col[j];
            float e = s[sn] + dn;
            e = (e > 0.f) ? e : NEG * e;
            const float ex = __expf(e - mx);
            const int jj = j - c0;
            ls[jj] = sn;
            lex[jj] = ex;
            dsum += ex;
        }
        __syncthreads();
        const int cnum = cend - c0;
        for (int jj = 0; jj < cnum; ++jj) {
            const int sn = ls[jj];
            const float ex = lex[jj];
            const ushort2 hv = *(const ushort2*)&h[(size_t)sn * 128 + lane * 2];
            acc0 = fmaf(ex, bf2f(hv.x), acc0);
            acc1 = fmaf(ex, bf2f(hv.y), acc1);
        }
        __syncthreads();
    }
#pragma unroll
    for (int off = 1; off < 64; off <<= 1) dsum += __shfl_xor(dsum, off);
    const float inv = 1.f / (dsum + 1e-16f);
    const int c = lane * 2;
    float2 o = make_float2(acc0 * inv + bias[c], acc1 * inv + bias[c + 1]);
    *(float2*)&y[(size_t)n * 128 + c] = o;
}

// ---------- BatchNorm ----------
__global__ __launch_bounds__(256) void bn_stats1(
    const float* __restrict__ y, float* __restrict__ partial, int nblocks) {
    const int b = blockIdx.x, t = threadIdx.x;
    const int c = t & 127;
    float sum = 0.f, sq = 0.f;
    for (int r = b * 2 + (t >> 7); r < N_NODES; r += nblocks * 2) {
        const float v = y[(size_t)r * 128 + c];
        sum += v;
        sq += v * v;
    }
    __shared__ float s1[256], s2[256];
    s1[t] = sum; s2[t] = sq;
    __syncthreads();
    if (t < 128) {
        partial[(size_t)b * 256 + c] = s1[t] + s1[t + 128];
        partial[(size_t)b * 256 + 128 + c] = s2[t] + s2[t + 128];
    }
}

__global__ __launch_bounds__(128) void bn_stats2(
    const float* __restrict__ partial, int nblocks,
    const float* __restrict__ gamma, const float* __restrict__ beta,
    float* __restrict__ stats) {
    const int c = threadIdx.x;
    float S = 0.f, Q = 0.f;
    for (int b = 0; b < nblocks; ++b) {
        S += partial[(size_t)b * 256 + c];
        Q += partial[(size_t)b * 256 + 128 + c];
    }
    const float mu = S / (float)N_NODES;
    const float var = Q / (float)N_NODES - mu * mu;
    const float sc = gamma[c] * rsqrtf(var + EPS_BN);
    stats[c] = sc;
    stats[128 + c] = beta[c] - mu * sc;
}

__global__ void bn_apply_bf16(const float* __restrict__ y,
                              const float* __restrict__ stats,
                              ushort* __restrict__ out) {
    const int i = blockIdx.x * 256 + threadIdx.x;
    const int e0 = i * 4;
    if (e0 >= M_PAD * 128) return;
    const int row = e0 >> 7;
    ushort4 o;
    if (row < N_NODES) {
        const float4 v = *(const float4*)&y[e0];
        const int c = e0 & 127;
        const float a = fmaxf(v.x * stats[c]     + stats[128 + c],     0.f);
        const float b = fmaxf(v.y * stats[c + 1] + stats[128 + c + 1], 0.f);
        const float cc = fmaxf(v.z * stats[c + 2] + stats[128 + c + 2], 0.f);
        const float d = fmaxf(v.w * stats[c + 3] + stats[128 + c + 3], 0.f);
        o = make_ushort4(f2bf(a), f2bf(b), f2bf(cc), f2bf(d));
    } else {
        o = make_ushort4(0, 0, 0, 0);
    }
    *(ushort4*)&out[e0] = o;
}

__global__ void bn_apply_out(const float* __restrict__ y,
                             const float* __restrict__ stats,
                             float* __restrict__ out) {
    const int i = blockIdx.x * blockDim.x + threadIdx.x;
    if (i < N_NODES * 128) {
        const int c = i & 127;
        out[i] = y[i] * stats[c] + stats[128 + c];
    }
}

// ---------- launch ----------
extern "C" void kernel_launch(void* const* d_in, const int* in_sizes, int n_in,
                              void* d_out, int out_size, void* d_ws, size_t ws_size,
                              hipStream_t stream) {
    const float* x = (const float*)d_in[0];
    const int* ei = (const int*)d_in[1];
    const int E = in_sizes[1] / 2;
    const int ET = E + N_NODES;

    const float* W[3]    = {(const float*)d_in[2], (const float*)d_in[8],  (const float*)d_in[14]};
    const float* ASRC[3] = {(const float*)d_in[3], (const float*)d_in[9],  (const float*)d_in[15]};
    const float* ADST[3] = {(const float*)d_in[4], (const float*)d_in[10], (const float*)d_in[16]};
    const float* BIAS[3] = {(const float*)d_in[5], (const float*)d_in[11], (const float*)d_in[17]};
    const float* GAM[3]  = {(const float*)d_in[6], (const float*)d_in[12], (const float*)d_in[18]};
    const float* BET[3]  = {(const float*)d_in[7], (const float*)d_in[13], (const float*)d_in[19]};

    char* base = (char*)d_ws;
    auto alloc = [&](size_t bytes) {
        char* p = base;
        base += (bytes + 255) & ~(size_t)255;
        return p;
    };
    ushort* hbf    = (ushort*)alloc((size_t)M_PAD * 512 * 2);
    ushort* Xbf    = (ushort*)alloc((size_t)M_PAD * 256 * 2);
    ushort* Wt     = (ushort*)alloc((size_t)512 * 256 * 2);
    float*  y      = (float*)alloc((size_t)N_NODES * 128 * 4);
    float*  s      = (float*)alloc((size_t)N_NODES * 4 * 4);
    float*  dsc    = (float*)alloc((size_t)N_NODES * 4 * 4);
    int*    rowptr = (int*)alloc((size_t)(N_NODES + 1) * 4);
    int*    col    = (int*)alloc((size_t)ET * 4);
    int*    cnt    = (int*)alloc((size_t)N_NODES * 4);          // reused as cursor
    int*    incl   = (int*)alloc((size_t)N_NODES * 4);
    int*    bsum   = (int*)alloc((size_t)64 * 4);
    float*  partial = (float*)alloc((size_t)256 * 256 * 4);
    float*  stats   = (float*)alloc((size_t)256 * 4);
    if ((size_t)(base - (char*)d_ws) > ws_size) return;

    const int eb = (ET + 255) / 256;
    const int nScanB = (N_NODES + 1023) / 1024;

    // --- CSR build ---
    hipMemsetAsync(cnt, 0, (size_t)N_NODES * 4, stream);
    edge_hist<<<eb, 256, 0, stream>>>(ei, E, cnt);
    scan_phase1<<<nScanB, 256, 0, stream>>>(cnt, incl, bsum, N_NODES);
    scan_phase2<<<1, 64, 0, stream>>>(bsum, nScanB);
    scan_phase3<<<(N_NODES + 255) / 256, 256, 0, stream>>>(incl, bsum, rowptr, cnt, N_NODES);
    edge_scatter<<<eb, 256, 0, stream>>>(ei, E, cnt, col);

    // --- layer-0 input to bf16 (padded) ---
    conv_x<<<(M_PAD * 256 / 4 + 255) / 256, 256, 0, stream>>>(x, Xbf);

    const int Hs[3]  = {4, 4, 1};
    const int Kin[3] = {256, 128, 128};

    for (int L = 0; L < 3; ++L) {
        const int H = Hs[L], K = Kin[L], Nc = H * 128;

        convT<<<(K * Nc + 255) / 256, 256, 0, stream>>>(W[L], Wt, K, Nc);
        dim3 ggrid(Nc / 64, M_PAD / 128);
        gemm_bf16<<<ggrid, 256, 0, stream>>>(Xbf, Wt, hbf, K, Nc);

        if (H == 4) {
            scores_kernel<4><<<N_NODES, 128, 0, stream>>>(hbf, ASRC[L], ADST[L], s, dsc);
            aggregate4<<<N_NODES, 64, 0, stream>>>(hbf, s, dsc, rowptr, col, BIAS[L], y);
        } else {
            scores_kernel<1><<<N_NODES, 128, 0, stream>>>(hbf, ASRC[L], ADST[L], s, dsc);
            aggregate1<<<N_NODES, 64, 0, stream>>>(hbf, s, dsc, rowptr, col, BIAS[L], y);
        }

        bn_stats1<<<256, 256, 0, stream>>>(y, partial, 256);
        bn_stats2<<<1, 128, 0, stream>>>(partial, 256, GAM[L], BET[L], stats);

        if (L < 2) {
            bn_apply_bf16<<<(M_PAD * 128 / 4 + 255) / 256, 256, 0, stream>>>(y, stats, Xbf);
        } else {
            bn_apply_out<<<(N_NODES * 128 + 255) / 256, 256, 0, stream>>>(y, stats, (float*)d_out);
        }
    }
}